// Round 1
// baseline (192.321 us; speedup 1.0000x reference)
//
#include <hip/hip_runtime.h>

// FeatureFuser: out = sigmoid( select(fused) ), where fused[b,y,x] =
//   refined[b,k_last,y,x] if pixel inside rect(b,k_last) for the largest such k,
//   else sampling[b,y,x].
// Shapes: sampling (32,1,512,512) f32, refined (32,4,1,512,512) f32,
//         regions (32,4,2) int32 (values 0/1). Rect = [r0*128, +384) x [r1*128, +384).
// Rect x-boundaries are multiples of 128 -> an aligned float4 never straddles
// a boundary, so each thread handles 4 consecutive pixels with one mask test.

#define HH 512
#define WW 512
#define KTOP 4
#define GH 128
#define WIN 384

__global__ __launch_bounds__(256) void featurefuser_kernel(
    const float* __restrict__ smap,      // (B,1,H,W)
    const float* __restrict__ rmaps,     // (B,K,1,H,W)
    const int*   __restrict__ regions,   // (B,K,2) int32
    float* __restrict__ out)             // (B,1,H,W)
{
    const int tid = blockIdx.x * blockDim.x + threadIdx.x;  // 0 .. 2M-1
    const int idx = tid << 2;            // flat pixel index (max 8.4M, fits int)
    const int x = idx & (WW - 1);
    const int y = (idx >> 9) & (HH - 1);
    const int b = idx >> 18;

    // sampling_map flat offset == idx (since C=1)
    const float* src = smap + idx;

    const int plane = (y << 9) + x;      // y*W + x
    #pragma unroll
    for (int k = 0; k < KTOP; ++k) {
        // regions[(b*K + k)*2 + {0,1}] — 8B-aligned pair, broadcast across wave
        const int2 r = ((const int2*)regions)[b * KTOP + k];
        int y0 = r.x * GH; y0 = y0 < 0 ? 0 : (y0 > HH ? HH : y0);
        int x0 = r.y * GH; x0 = x0 < 0 ? 0 : (x0 > WW ? WW : x0);
        const int y1 = (y0 + WIN > HH) ? HH : (y0 + WIN);
        const int x1 = (x0 + WIN > WW) ? WW : (x0 + WIN);
        const bool inside = (y >= y0) & (y < y1) & (x >= x0) & (x < x1);
        const float* cand = rmaps + (((b * KTOP + k) << 18) + plane);
        src = inside ? cand : src;       // later k overrides (reference where-chain)
    }

    const float4 v = *(const float4*)src;
    float4 o;
    o.x = 1.0f / (1.0f + __expf(-v.x));
    o.y = 1.0f / (1.0f + __expf(-v.y));
    o.z = 1.0f / (1.0f + __expf(-v.z));
    o.w = 1.0f / (1.0f + __expf(-v.w));
    *(float4*)(out + idx) = o;
}

extern "C" void kernel_launch(void* const* d_in, const int* in_sizes, int n_in,
                              void* d_out, int out_size, void* d_ws, size_t ws_size,
                              hipStream_t stream) {
    const float* smap    = (const float*)d_in[0];
    const float* rmaps   = (const float*)d_in[1];
    const int*   regions = (const int*)d_in[2];
    float* out = (float*)d_out;

    // out_size = 32*512*512 = 8388608; 4 px/thread, 256 thr/block -> 8192 blocks
    const int threads = out_size / 4;            // 2,097,152
    const int block = 256;
    const int grid = (threads + block - 1) / block;
    featurefuser_kernel<<<grid, block, 0, stream>>>(smap, rmaps, regions, out);
}